// Round 5
// baseline (156.132 us; speedup 1.0000x reference)
//
#include <hip/hip_runtime.h>
#include <hip/hip_bf16.h>

#define DDIM 256
#define NROWS 8192
#define LOG2E5 7.2134752044448170f   // 5 / ln(2): exp(5x) = exp2(LOG2E5 * x)

typedef __attribute__((ext_vector_type(8))) __bf16 bf16x8;
typedef __attribute__((ext_vector_type(4))) float floatx4;

// Fragment-order layout: for 16-row group R (rows 16R+m) and k-granule G
// (k = 32G + q*8 + j), lane (m = lane&15, q = lane>>4) owns 8 bf16 at
//   frag_ptr = X + ((R*8 + G)*64 + lane)*8
// A wave's fragment load is one contiguous 1 KB global_load_dwordx4 stream.

// Kernel 1: L2-normalize 16 rows of U and P (one R-group per block), compute
// pos_sim, write Af/Pf in fragment order, zero rowsum / out / counter.
__global__ __launch_bounds__(256) void normalize_repack(
    const float* __restrict__ U, const float* __restrict__ P,
    unsigned short* __restrict__ Af, unsigned short* __restrict__ Pf,
    float* __restrict__ possim, float* __restrict__ rowsum,
    float* __restrict__ out, int* __restrict__ counter)
{
    __shared__ unsigned short Ut[16 * 264];   // +8 pad: repack reads conflict-light
    __shared__ unsigned short Pt[16 * 264];
    const int tid = threadIdx.x;
    const int R   = blockIdx.x;            // 0..511
    const int r16 = tid >> 4;              // row within group, 0..15
    const int c   = tid & 15;              // 16 threads per row
    const int row = R * 16 + r16;

    if (R == 0 && tid == 0) { out[0] = 0.0f; counter[0] = 0; }
    if (c == 0) rowsum[row] = 0.0f;

    float4 u4[4], p4[4];
    float su = 0.0f, sp = 0.0f, up = 0.0f;
    #pragma unroll
    for (int j = 0; j < 4; ++j) {
        const size_t base = (size_t)row * DDIM + c * 16 + j * 4;
        u4[j] = *(const float4*)(U + base);
        p4[j] = *(const float4*)(P + base);
        su += u4[j].x*u4[j].x + u4[j].y*u4[j].y + u4[j].z*u4[j].z + u4[j].w*u4[j].w;
        sp += p4[j].x*p4[j].x + p4[j].y*p4[j].y + p4[j].z*p4[j].z + p4[j].w*p4[j].w;
        up += u4[j].x*p4[j].x + u4[j].y*p4[j].y + u4[j].z*p4[j].z + u4[j].w*p4[j].w;
    }
    #pragma unroll
    for (int d = 1; d < 16; d <<= 1) {     // reduce within the row's 16 lanes
        su += __shfl_xor(su, d);
        sp += __shfl_xor(sp, d);
        up += __shfl_xor(up, d);
    }
    const float iu = rsqrtf(fmaxf(su, 1e-24f));
    const float ip = rsqrtf(fmaxf(sp, 1e-24f));
    if (c == 0) possim[row] = up * iu * ip;

    #pragma unroll
    for (int j = 0; j < 4; ++j) {
        union { ushort4 s4; __hip_bfloat16 h[4]; } cu, cp;
        cu.h[0] = __float2bfloat16(u4[j].x * iu); cu.h[1] = __float2bfloat16(u4[j].y * iu);
        cu.h[2] = __float2bfloat16(u4[j].z * iu); cu.h[3] = __float2bfloat16(u4[j].w * iu);
        cp.h[0] = __float2bfloat16(p4[j].x * ip); cp.h[1] = __float2bfloat16(p4[j].y * ip);
        cp.h[2] = __float2bfloat16(p4[j].z * ip); cp.h[3] = __float2bfloat16(p4[j].w * ip);
        *(ushort4*)&Ut[r16 * 264 + c * 16 + j * 4] = cu.s4;
        *(ushort4*)&Pt[r16 * 264 + c * 16 + j * 4] = cp.s4;
    }
    __syncthreads();

    // Repack: wave w writes granules G = 2w, 2w+1 for both matrices.
    // LDS read: lane (m,q) <- tile[m][G*32 + q*8 .. +7]; store contiguous 1 KB.
    const int lane = tid & 63;
    const int wv   = tid >> 6;
    const int m = lane & 15, q = lane >> 4;
    #pragma unroll
    for (int g = 0; g < 2; ++g) {
        const int G = wv * 2 + g;
        const bf16x8 ua = *(const bf16x8*)&Ut[m * 264 + G * 32 + q * 8];
        const bf16x8 pa = *(const bf16x8*)&Pt[m * 264 + G * 32 + q * 8];
        const size_t o = ((size_t)(R * 8 + G) * 64 + lane) * 8;
        *(bf16x8*)(Af + o) = ua;
        *(bf16x8*)(Pf + o) = pa;
    }
}

// Kernel 2: barrier-free GEMM + exp-rowsum + fused finalize.
// 512 blocks (2/CU), 4 waves (2x2). Block = 128-row stripe x 1024-col octant
// (oct = blockIdx&7 == XCD id for L2 locality: all blocks on an XCD stream
// the SAME B octant). A-frags register-resident (128 VGPR); B-frags loaded
// per-ks as contiguous 1 KB coalesced global loads, no LDS, no syncthreads
// in the K/N loop -> waves free-run, MFMA interleaves with loads via
// compiler vmcnt(N); 2 blocks/CU co-schedule (m114).
__global__ __launch_bounds__(256, 2) void sim_exp_rowsum(
    const unsigned short* __restrict__ Af,
    const unsigned short* __restrict__ Pf,
    float* __restrict__ rowsum,
    const float* __restrict__ possim,
    int* __restrict__ counter,
    float* __restrict__ out)
{
    __shared__ float ws4[4];
    __shared__ int ticket_s;
    const int tid  = threadIdx.x;
    const int lane = tid & 63;
    const int wv   = tid >> 6;
    const int wr   = wv >> 1, wc = wv & 1;
    const int m = lane & 15, q = lane >> 4;

    const int oct    = blockIdx.x & 7;
    const int stripe = blockIdx.x >> 3;

    // A fragments: rows stripe*128 + wr*64 + t*16 + m, all K. 32 frags.
    bf16x8 afr[4][8];
    #pragma unroll
    for (int t = 0; t < 4; ++t)
        #pragma unroll
        for (int ks = 0; ks < 8; ++ks)
            afr[t][ks] = *(const bf16x8*)(Af +
                ((size_t)((stripe * 8 + wr * 4 + t) * 8 + ks) * 64 + lane) * 8);

    float rowpart[4][4];
    #pragma unroll
    for (int t = 0; t < 4; ++t)
        #pragma unroll
        for (int r = 0; r < 4; ++r)
            rowpart[t][r] = 0.0f;

    for (int i = 0; i < 16; ++i) {         // 16 col-tiles of 64 in the octant
        const int RB0 = oct * 64 + i * 4 + wc * 2;   // 16-col group for u=0
        const unsigned short* B0 = Pf + ((size_t)RB0 * 8 * 64 + lane) * 8;

        floatx4 acc[4][2];
        #pragma unroll
        for (int t = 0; t < 4; ++t) {
            acc[t][0] = {0.0f, 0.0f, 0.0f, 0.0f};
            acc[t][1] = {0.0f, 0.0f, 0.0f, 0.0f};
        }
        #pragma unroll
        for (int ks = 0; ks < 8; ++ks) {
            const bf16x8 b0 = *(const bf16x8*)(B0 + (size_t)ks * 512);
            const bf16x8 b1 = *(const bf16x8*)(B0 + (size_t)(8 + ks) * 512);
            #pragma unroll
            for (int t = 0; t < 4; ++t) {
                acc[t][0] = __builtin_amdgcn_mfma_f32_16x16x32_bf16(
                    afr[t][ks], b0, acc[t][0], 0, 0, 0);
                acc[t][1] = __builtin_amdgcn_mfma_f32_16x16x32_bf16(
                    afr[t][ks], b1, acc[t][1], 0, 0, 0);
            }
        }
        // exp(5*sim) = exp2(LOG2E5*sim); C/D: col = m, row = q*4 + r (+t*16)
        #pragma unroll
        for (int t = 0; t < 4; ++t)
            #pragma unroll
            for (int r = 0; r < 4; ++r)
                rowpart[t][r] += exp2f(LOG2E5 * acc[t][0][r])
                               + exp2f(LOG2E5 * acc[t][1][r]);
    }

    // Reduce 16 column-lanes, one atomicAdd per row per wave.
    #pragma unroll
    for (int t = 0; t < 4; ++t) {
        #pragma unroll
        for (int r = 0; r < 4; ++r) {
            float s = rowpart[t][r];
            s += __shfl_xor(s, 1);
            s += __shfl_xor(s, 2);
            s += __shfl_xor(s, 4);
            s += __shfl_xor(s, 8);
            if (m == 0) {
                const int grow = stripe * 128 + wr * 64 + t * 16 + q * 4 + r;
                atomicAdd(&rowsum[grow], s);
            }
        }
    }

    // Fused finalize: last block computes loss = mean(log(rowsum) - 5*possim).
    __threadfence();
    __syncthreads();
    if (tid == 0)
        ticket_s = __hip_atomic_fetch_add(counter, 1, __ATOMIC_ACQ_REL,
                                          __HIP_MEMORY_SCOPE_AGENT);
    __syncthreads();
    if (ticket_s == 511) {
        float part = 0.0f;
        for (int idx = tid; idx < NROWS; idx += 256) {
            const float rs = __hip_atomic_load(&rowsum[idx], __ATOMIC_RELAXED,
                                               __HIP_MEMORY_SCOPE_AGENT);
            part += __logf(rs) - 5.0f * possim[idx];
        }
        #pragma unroll
        for (int d = 1; d < 64; d <<= 1) part += __shfl_xor(part, d);
        if (lane == 0) ws4[wv] = part;
        __syncthreads();
        if (tid == 0)
            out[0] = (ws4[0] + ws4[1] + ws4[2] + ws4[3]) * (1.0f / (float)NROWS);
    }
}

extern "C" void kernel_launch(void* const* d_in, const int* in_sizes, int n_in,
                              void* d_out, int out_size, void* d_ws, size_t ws_size,
                              hipStream_t stream) {
    const float* U = (const float*)d_in[0];
    const float* P = (const float*)d_in[1];
    float* out = (float*)d_out;
    char* ws = (char*)d_ws;
    // ws: Af bf16 frag-order (4 MB) | Pf (4 MB) | rowsum (32 KB) | possim (32 KB) | counter
    unsigned short* Af = (unsigned short*)ws;
    unsigned short* Pf = (unsigned short*)(ws + 4194304);
    float* rowsum = (float*)(ws + 8388608);
    float* possim = (float*)(ws + 8388608 + 32768);
    int* counter  = (int*)(ws + 8388608 + 65536);

    normalize_repack<<<NROWS / 16, 256, 0, stream>>>(U, P, Af, Pf, possim, rowsum,
                                                     out, counter);
    sim_exp_rowsum<<<512, 256, 0, stream>>>(Af, Pf, rowsum, possim, counter, out);
}